// Round 4
// baseline (500.575 us; speedup 1.0000x reference)
//
#include <hip/hip_runtime.h>
#include <hip/hip_bf16.h>

// ---------------------------------------------------------------------------
// FusionCrossAttention: out = softmax((x Wq^T)(kv Wk^T)^T / sqrt(hd)) (kv Wv^T) Wo^T
// B=4, T_q=1024, T_kv=4096, D=1024, H=16, hd=64
// Intermediates bf16, accumulation f32 via MFMA. Softmax scale (and log2e)
// folded into the W_q bf16 conversion.
// ---------------------------------------------------------------------------

typedef __attribute__((ext_vector_type(4))) float f32x4;
typedef __attribute__((ext_vector_type(16))) float f32x16;
typedef __attribute__((ext_vector_type(8))) short bf16x8;

__device__ __forceinline__ unsigned short f2bf(float f) {
  unsigned u = __float_as_uint(f);
  u = (u + 0x7fffu + ((u >> 16) & 1u)) >> 16;   // round-to-nearest-even
  return (unsigned short)u;
}

// v_permlane32_swap_b32: x' = [x(0:31), y(0:31)], y' = [x(32:63), y(32:63)]
__device__ __forceinline__ void pl32swap(unsigned& x, unsigned& y) {
  asm volatile("v_permlane32_swap_b32 %0, %1" : "+v"(x), "+v"(y));
}

#define GLD_LDS16(g, l)                                                     \
  __builtin_amdgcn_global_load_lds(                                        \
      (const __attribute__((address_space(1))) unsigned int*)(const void*)(g), \
      (__attribute__((address_space(3))) unsigned int*)(void*)(l), 16, 0, 0)

// ---------------------------------------------------------------------------
// Fused f32 -> bf16 conversion for all six inputs (one launch).
// W_q additionally scaled by 1/sqrt(64) * log2(e) BEFORE rounding.
// ---------------------------------------------------------------------------
__global__ void cvt_all(const float* __restrict__ q, const float* __restrict__ kv,
                        const float* __restrict__ wq, const float* __restrict__ wk,
                        const float* __restrict__ wv, const float* __restrict__ wo,
                        unsigned short* __restrict__ q_bf,
                        unsigned short* __restrict__ kv_bf,
                        unsigned short* __restrict__ wq_bf,
                        unsigned short* __restrict__ wk_bf,
                        unsigned short* __restrict__ wv_bf,
                        unsigned short* __restrict__ wo_bf) {
  const int QN = 4194304, KVN = 16777216, WN = 1048576;
  const float SC = 0.125f * 1.44269504088896f;
  int total_quads = (QN + KVN + 4 * WN) >> 2;
  int stride = gridDim.x * blockDim.x;
  for (int t = blockIdx.x * blockDim.x + threadIdx.x; t < total_quads; t += stride) {
    int i = t << 2;
    const float* src;
    unsigned short* dst;
    float sc = 1.0f;
    int off;
    if (i < QN) { src = q; dst = q_bf; off = i; }
    else if (i < QN + KVN) { src = kv; dst = kv_bf; off = i - QN; }
    else if (i < QN + KVN + WN) { src = wq; dst = wq_bf; off = i - QN - KVN; sc = SC; }
    else if (i < QN + KVN + 2 * WN) { src = wk; dst = wk_bf; off = i - QN - KVN - WN; }
    else if (i < QN + KVN + 3 * WN) { src = wv; dst = wv_bf; off = i - QN - KVN - 2 * WN; }
    else { src = wo; dst = wo_bf; off = i - QN - KVN - 3 * WN; }
    float4 v = *(const float4*)(src + off);
    ushort4 r;
    r.x = f2bf(v.x * sc); r.y = f2bf(v.y * sc);
    r.z = f2bf(v.z * sc); r.w = f2bf(v.w * sc);
    *(ushort4*)(dst + off) = r;
  }
}

// ---------------------------------------------------------------------------
// 128x128x(K) GEMM, C[i][j] = sum_k A[i][k] * Bt[j][k]   (B^T input layout)
// m97 structure (unchanged this round).
// ---------------------------------------------------------------------------
template <int WRITE_BF16>
__global__ __launch_bounds__(256) void gemm_bt(
    const unsigned short* __restrict__ A, const unsigned short* __restrict__ Bt,
    void* __restrict__ Cp, int M, int N, int K, int ldc) {
  __shared__ __align__(16) unsigned short Ash[4096];  // [128][32]
  __shared__ __align__(16) unsigned short Bsh[4096];  // [128][32]

  int tiles_n = N >> 7;
  int nwg = gridDim.x;
  int wg = blockIdx.x;
  int cpx = nwg >> 3;
  wg = (wg & 7) * cpx + (wg >> 3);          // XCD-aware swizzle
  int tm = wg / tiles_n, tn = wg - tm * tiles_n;

  int tid = threadIdx.x;
  int lane = tid & 63, wave = tid >> 6;
  int wr = wave >> 1, wc = wave & 1;
  int brow = tm << 7, bcol = tn << 7;

  int fr = lane & 15, fg = lane >> 4;
  int swz = (fr >> 1) & 3;

  int srow = lane >> 2;
  int sg = (lane & 3) ^ ((srow >> 1) & 3);

  const unsigned short* aG0 = A + (size_t)(brow + wave * 32 + srow) * K + sg * 8;
  const unsigned short* aG1 = A + (size_t)(brow + wave * 32 + 16 + srow) * K + sg * 8;
  const unsigned short* bG0 = Bt + (size_t)(bcol + wave * 32 + srow) * K + sg * 8;
  const unsigned short* bG1 = Bt + (size_t)(bcol + wave * 32 + 16 + srow) * K + sg * 8;
  unsigned short* aL0 = Ash + wave * 1024;
  unsigned short* aL1 = Ash + wave * 1024 + 512;
  unsigned short* bL0 = Bsh + wave * 1024;
  unsigned short* bL1 = Bsh + wave * 1024 + 512;

  const f32x4 zero4 = {0.f, 0.f, 0.f, 0.f};
  f32x4 acc[4][4];
#pragma unroll
  for (int m = 0; m < 4; ++m)
#pragma unroll
    for (int n = 0; n < 4; ++n) acc[m][n] = zero4;

  for (int k0 = 0; k0 < K; k0 += 32) {
    GLD_LDS16(aG0 + k0, aL0);
    GLD_LDS16(aG1 + k0, aL1);
    GLD_LDS16(bG0 + k0, bL0);
    GLD_LDS16(bG1 + k0, bL1);
    __syncthreads();

    bf16x8 af[4], bfr[4];
#pragma unroll
    for (int m = 0; m < 4; ++m) {
      int r = wr * 64 + m * 16 + fr;
      af[m] = *(const bf16x8*)(Ash + r * 32 + ((fg ^ swz) * 8));
    }
#pragma unroll
    for (int n = 0; n < 4; ++n) {
      int r = wc * 64 + n * 16 + fr;
      bfr[n] = *(const bf16x8*)(Bsh + r * 32 + ((fg ^ swz) * 8));
    }
#pragma unroll
    for (int m = 0; m < 4; ++m)
#pragma unroll
      for (int n = 0; n < 4; ++n)
        acc[m][n] =
            __builtin_amdgcn_mfma_f32_16x16x32_bf16(af[m], bfr[n], acc[m][n], 0, 0, 0);
    __syncthreads();
  }

  int crow = brow + wr * 64 + fg * 4;
  int ccol = bcol + wc * 64 + fr;
#pragma unroll
  for (int m = 0; m < 4; ++m)
#pragma unroll
    for (int n = 0; n < 4; ++n)
#pragma unroll
      for (int j = 0; j < 4; ++j) {
        size_t off = (size_t)(crow + m * 16 + j) * ldc + (ccol + n * 16);
        if (WRITE_BF16)
          ((unsigned short*)Cp)[off] = f2bf(acc[m][n][j]);
        else
          ((float*)Cp)[off] = acc[m][n][j];
      }
}

// ---------------------------------------------------------------------------
// Flash attention v4: swapped QK^T + 32x32x16 MFMA, softmax fully in-register.
// Grid: 1024 blocks = (b:4, h:16, qtile:16 of 64 rows), XCD-swizzled.
// Block: 128 threads / 2 waves; each wave owns 32 q-rows. KVBLK=128.
//   S^T = mfma(A=K_frag, B=Q_frag): lane's col = q = lane&31 (lane-local row!),
//   rows kv = kt*32 + (r&3)+8*(r>>2)+4*hi.  Softmax: per-lane tree max +
//   one shfl_xor(32).  P -> bf16 B-fragments in-register via cvt_pk +
//   v_permlane32_swap (no LDS round-trip).  O^T = mfma(A=V^T_frag, B=P_frag).
//   Row-sum via mfma(ones, P).  K staged [128][64] granule-swizzled
//   g^= (r ^ 2*(r>>3))&7; V^T staged [64][128] g ^= (r>>1)&14 -- both give
//   all-64-lane distinct 16B windows on fragment reads (conflict-free).
// LDS: 32 KB -> 4 blocks/CU (8 waves/CU).
// ---------------------------------------------------------------------------
__global__ __launch_bounds__(128) void attn_fwd(
    const unsigned short* __restrict__ qp,  // (4096, 1024), pre-scaled by SC
    const unsigned short* __restrict__ kp,  // (16384, 1024)
    const unsigned short* __restrict__ vt,  // (1024, 16384) = V^T per (b,h)
    unsigned short* __restrict__ ao) {      // (4096, 1024)
  __shared__ __align__(16) unsigned short Ksh[128 * 64];   // 16 KB
  __shared__ __align__(16) unsigned short Vsh[64 * 128];   // 16 KB

  int idx = (blockIdx.x & 7) * 128 + (blockIdx.x >> 3);
  int qt = idx & 15;
  int h = (idx >> 4) & 15;
  int b = idx >> 8;
  int tid = threadIdx.x;
  int lane = tid & 63, w = tid >> 6;  // w in 0..1
  int q5 = lane & 31, hi = lane >> 5;

  // ---- Q fragments (B-operand, 32x32x16): lane q5, k = s*16 + hi*8 + e ----
  const unsigned short* qptr =
      qp + (size_t)(b * 1024 + qt * 64 + w * 32 + q5) * 1024 + h * 64 + hi * 8;
  bf16x8 qf[4];
#pragma unroll
  for (int s = 0; s < 4; ++s) qf[s] = *(const bf16x8*)(qptr + s * 16);

  bf16x8 ones;
#pragma unroll
  for (int e = 0; e < 8; ++e) ones[e] = (short)0x3F80;  // 1.0 bf16

  f32x16 O[2], rsum;
#pragma unroll
  for (int r = 0; r < 16; ++r) { O[0][r] = 0.f; O[1][r] = 0.f; rsum[r] = 0.f; }
  float mrun = -1e30f;

  // ---- staging source pointers (pre-swizzled granules) ----
  // K: rows kv (128), 8 granules/row; dest slot g holds src granule g^swzK(row)
  const unsigned short* kS[8];
#pragma unroll
  for (int i = 0; i < 8; ++i) {
    int row = w * 64 + i * 8 + (lane >> 3);
    int g = (lane & 7) ^ ((row ^ (2 * (row >> 3))) & 7);
    kS[i] = kp + (size_t)(b * 4096 + row) * 1024 + h * 64 + g * 8;
  }
  // V^T: rows d (64), 16 granules/row; dest slot g holds src granule g^swzV(row)
  const unsigned short* vS[8];
#pragma unroll
  for (int i = 0; i < 8; ++i) {
    int row = w * 32 + i * 4 + (lane >> 4);
    int g = (lane & 15) ^ ((row >> 1) & 14);
    vS[i] = vt + (size_t)(h * 64 + row) * 16384 + b * 4096 + g * 8;
  }

  // ---- fragment-read offsets (loop-invariant, hoisted) ----
  int xk = hi ^ ((q5 ^ (2 * (q5 >> 3))) & 7);
  int koff[4];
#pragma unroll
  for (int s = 0; s < 4; ++s) koff[s] = q5 * 64 + (((2 * s) ^ xk) * 8);
  int xv = hi ^ ((q5 >> 1) & 14);
  int voff[4][2];
#pragma unroll
  for (int kt = 0; kt < 4; ++kt)
#pragma unroll
    for (int p = 0; p < 2; ++p)
      voff[kt][p] = q5 * 128 + (((4 * kt + 2 * p) ^ xv) * 8);

  for (int it = 0; it < 32; ++it) {
    // ---- stage K (16KB) + V (16KB), 8 issues each per thread ----
#pragma unroll
    for (int i = 0; i < 8; ++i) GLD_LDS16(kS[i], Ksh + w * 4096 + i * 512);
#pragma unroll
    for (int i = 0; i < 8; ++i) GLD_LDS16(vS[i], Vsh + w * 4096 + i * 512);
#pragma unroll
    for (int i = 0; i < 8; ++i) { kS[i] += 131072; vS[i] += 128; }
    __syncthreads();  // drains vmcnt; LDS tiles ready

    // ---- S^T = K Q^T : 4 kv-tiles x 4 k-slices ----
    f32x16 S[4];
#pragma unroll
    for (int kt = 0; kt < 4; ++kt)
#pragma unroll
      for (int r = 0; r < 16; ++r) S[kt][r] = 0.f;
    __builtin_amdgcn_s_setprio(1);
#pragma unroll
    for (int kt = 0; kt < 4; ++kt)
#pragma unroll
      for (int s = 0; s < 4; ++s) {
        bf16x8 kf = *(const bf16x8*)(Ksh + kt * 2048 + koff[s]);
        S[kt] = __builtin_amdgcn_mfma_f32_32x32x16_bf16(kf, qf[s], S[kt], 0, 0, 0);
      }
    __builtin_amdgcn_s_setprio(0);

    // ---- lane-local row max (tree) + one cross-half shuffle ----
    float t[16];
#pragma unroll
    for (int r = 0; r < 16; ++r)
      t[r] = fmaxf(fmaxf(S[0][r], S[1][r]), fmaxf(S[2][r], S[3][r]));
#pragma unroll
    for (int st = 8; st >= 1; st >>= 1)
#pragma unroll
      for (int r = 0; r < 8; ++r)
        if (r < st) t[r] = fmaxf(t[r], t[r + st]);
    float cmax = fmaxf(t[0], __shfl_xor(t[0], 32));

    // ---- rescale only when running max grows (skip is exact) ----
    if (__any(cmax > mrun)) {
      float mn = fmaxf(mrun, cmax);
      float fsc = exp2f(mrun - mn);
      mrun = mn;
#pragma unroll
      for (int r = 0; r < 16; ++r) {
        rsum[r] *= fsc; O[0][r] *= fsc; O[1][r] *= fsc;
      }
    }

    // ---- per kv-tile: exp2, pack P to B-frags in-register, rsum + PV ----
#pragma unroll
    for (int kt = 0; kt < 4; ++kt) {
      float p[16];
#pragma unroll
      for (int r = 0; r < 16; ++r) p[r] = exp2f(S[kt][r] - mrun);
      unsigned u[8];
#pragma unroll
      for (int i = 0; i < 8; ++i) {
        __hip_bfloat162 pk = __float22bfloat162_rn(float2{p[2 * i], p[2 * i + 1]});
        u[i] = *reinterpret_cast<unsigned*>(&pk);
      }
      // redistribute C-layout -> B-layout across the lane32 halves
      pl32swap(u[0], u[2]);
      pl32swap(u[1], u[3]);
      pl32swap(u[4], u[6]);
      pl32swap(u[5], u[7]);
      union PU { unsigned uu[4]; bf16x8 v; };
      PU a0; a0.uu[0] = u[0]; a0.uu[1] = u[1]; a0.uu[2] = u[2]; a0.uu[3] = u[3];
      PU a1; a1.uu[0] = u[4]; a1.uu[1] = u[5]; a1.uu[2] = u[6]; a1.uu[3] = u[7];
      bf16x8 pf0 = a0.v, pf1 = a1.v;

      __builtin_amdgcn_s_setprio(1);
      rsum = __builtin_amdgcn_mfma_f32_32x32x16_bf16(ones, pf0, rsum, 0, 0, 0);
      rsum = __builtin_amdgcn_mfma_f32_32x32x16_bf16(ones, pf1, rsum, 0, 0, 0);
#pragma unroll
      for (int dt = 0; dt < 2; ++dt) {
        bf16x8 vf0 = *(const bf16x8*)(Vsh + voff[kt][0] + dt * 4096);
        bf16x8 vf1 = *(const bf16x8*)(Vsh + voff[kt][1] + dt * 4096);
        O[dt] = __builtin_amdgcn_mfma_f32_32x32x16_bf16(vf0, pf0, O[dt], 0, 0, 0);
        O[dt] = __builtin_amdgcn_mfma_f32_32x32x16_bf16(vf1, pf1, O[dt], 0, 0, 0);
      }
      __builtin_amdgcn_s_setprio(0);
    }
    __syncthreads();  // all LDS reads done before next stage overwrites
  }

  // ---- normalize + store: lane q5 owns one q-row; d = dt*32+8*j2+4*hi+t ----
  float inv = 1.0f / rsum[0];
  size_t obase = (size_t)(b * 1024 + qt * 64 + w * 32 + q5) * 1024 + h * 64;
#pragma unroll
  for (int dt = 0; dt < 2; ++dt)
#pragma unroll
    for (int j2 = 0; j2 < 4; ++j2) {
      ushort4 pk;
      pk.x = f2bf(O[dt][4 * j2 + 0] * inv);
      pk.y = f2bf(O[dt][4 * j2 + 1] * inv);
      pk.z = f2bf(O[dt][4 * j2 + 2] * inv);
      pk.w = f2bf(O[dt][4 * j2 + 3] * inv);
      *(ushort4*)(ao + obase + dt * 32 + j2 * 8 + hi * 4) = pk;
    }
}

// ---------------------------------------------------------------------------
// Launcher. Workspace layout (128 MiB):
//   [0,8)    q_bf     [8,40)  kv_bf    [40,48) weights bf16 x4
//   [48,56)  qproj    [56,88) kproj    [88,120) v^T proj   [120,128) attn out
// ---------------------------------------------------------------------------
extern "C" void kernel_launch(void* const* d_in, const int* in_sizes, int n_in,
                              void* d_out, int out_size, void* d_ws, size_t ws_size,
                              hipStream_t stream) {
  const float* query = (const float*)d_in[0];
  const float* kvs = (const float*)d_in[1];
  const float* wq = (const float*)d_in[2];
  const float* wk = (const float*)d_in[3];
  const float* wv = (const float*)d_in[4];
  const float* wo = (const float*)d_in[5];
  float* out = (float*)d_out;
  char* ws = (char*)d_ws;
  const size_t MB = 1ull << 20;

  unsigned short* q_bf = (unsigned short*)(ws + 0 * MB);
  unsigned short* kv_bf = (unsigned short*)(ws + 8 * MB);
  unsigned short* wq_bf = (unsigned short*)(ws + 40 * MB);
  unsigned short* wk_bf = (unsigned short*)(ws + 42 * MB);
  unsigned short* wv_bf = (unsigned short*)(ws + 44 * MB);
  unsigned short* wo_bf = (unsigned short*)(ws + 46 * MB);
  unsigned short* qp = (unsigned short*)(ws + 48 * MB);
  unsigned short* kp = (unsigned short*)(ws + 56 * MB);
  unsigned short* vt = (unsigned short*)(ws + 88 * MB);
  unsigned short* ao = (unsigned short*)(ws + 120 * MB);

  cvt_all<<<2048, 256, 0, stream>>>(query, kvs, wq, wk, wv, wo, q_bf, kv_bf,
                                    wq_bf, wk_bf, wv_bf, wo_bf);

  // q = query @ (Wq*SC)^T       (4096 x 1024)
  gemm_bt<1><<<256, 256, 0, stream>>>(q_bf, wq_bf, qp, 4096, 1024, 1024, 1024);
  // k = kv @ Wk^T               (16384 x 1024)
  gemm_bt<1><<<1024, 256, 0, stream>>>(kv_bf, wk_bf, kp, 16384, 1024, 1024, 1024);
  // v^T = Wv @ kv^T             (1024 x 16384)
  gemm_bt<1><<<1024, 256, 0, stream>>>(wv_bf, kv_bf, vt, 1024, 16384, 1024, 16384);

  attn_fwd<<<1024, 128, 0, stream>>>(qp, kp, vt, ao);

  // out = attn_out @ Wo^T       (4096 x 1024) f32
  gemm_bt<0><<<256, 256, 0, stream>>>(ao, wo_bf, out, 4096, 1024, 1024, 1024);
}

// Round 5
// 445.827 us; speedup vs baseline: 1.1228x; 1.1228x over previous
//
#include <hip/hip_runtime.h>
#include <hip/hip_bf16.h>

// ---------------------------------------------------------------------------
// FusionCrossAttention: out = softmax((x Wq^T)(kv Wk^T)^T / sqrt(hd)) (kv Wv^T) Wo^T
// B=4, T_q=1024, T_kv=4096, D=1024, H=16, hd=64
// Intermediates bf16, accumulation f32 via MFMA. Softmax scale (and log2e)
// folded into the W_q bf16 conversion.
// ---------------------------------------------------------------------------

typedef __attribute__((ext_vector_type(4))) float f32x4;
typedef __attribute__((ext_vector_type(16))) float f32x16;
typedef __attribute__((ext_vector_type(8))) short bf16x8;

__device__ __forceinline__ unsigned short f2bf(float f) {
  unsigned u = __float_as_uint(f);
  u = (u + 0x7fffu + ((u >> 16) & 1u)) >> 16;   // round-to-nearest-even
  return (unsigned short)u;
}

// v_permlane32_swap_b32: x' = [x(0:31), y(0:31)], y' = [x(32:63), y(32:63)]
__device__ __forceinline__ void pl32swap(unsigned& x, unsigned& y) {
  asm volatile("v_permlane32_swap_b32 %0, %1" : "+v"(x), "+v"(y));
}

#define GLD_LDS16(g, l)                                                     \
  __builtin_amdgcn_global_load_lds(                                        \
      (const __attribute__((address_space(1))) unsigned int*)(const void*)(g), \
      (__attribute__((address_space(3))) unsigned int*)(void*)(l), 16, 0, 0)

// ---------------------------------------------------------------------------
// Fused f32 -> bf16 conversion for all six inputs (one launch).
// W_q additionally scaled by 1/sqrt(64) * log2(e) BEFORE rounding.
// ---------------------------------------------------------------------------
__global__ void cvt_all(const float* __restrict__ q, const float* __restrict__ kv,
                        const float* __restrict__ wq, const float* __restrict__ wk,
                        const float* __restrict__ wv, const float* __restrict__ wo,
                        unsigned short* __restrict__ q_bf,
                        unsigned short* __restrict__ kv_bf,
                        unsigned short* __restrict__ wq_bf,
                        unsigned short* __restrict__ wk_bf,
                        unsigned short* __restrict__ wv_bf,
                        unsigned short* __restrict__ wo_bf) {
  const int QN = 4194304, KVN = 16777216, WN = 1048576;
  const float SC = 0.125f * 1.44269504088896f;
  int total_quads = (QN + KVN + 4 * WN) >> 2;
  int stride = gridDim.x * blockDim.x;
  for (int t = blockIdx.x * blockDim.x + threadIdx.x; t < total_quads; t += stride) {
    int i = t << 2;
    const float* src;
    unsigned short* dst;
    float sc = 1.0f;
    int off;
    if (i < QN) { src = q; dst = q_bf; off = i; }
    else if (i < QN + KVN) { src = kv; dst = kv_bf; off = i - QN; }
    else if (i < QN + KVN + WN) { src = wq; dst = wq_bf; off = i - QN - KVN; sc = SC; }
    else if (i < QN + KVN + 2 * WN) { src = wk; dst = wk_bf; off = i - QN - KVN - WN; }
    else if (i < QN + KVN + 3 * WN) { src = wv; dst = wv_bf; off = i - QN - KVN - 2 * WN; }
    else { src = wo; dst = wo_bf; off = i - QN - KVN - 3 * WN; }
    float4 v = *(const float4*)(src + off);
    ushort4 r;
    r.x = f2bf(v.x * sc); r.y = f2bf(v.y * sc);
    r.z = f2bf(v.z * sc); r.w = f2bf(v.w * sc);
    *(ushort4*)(dst + off) = r;
  }
}

// ---------------------------------------------------------------------------
// 128x128x(K) GEMM, C[i][j] = sum_k A[i][k] * Bt[j][k]   (B^T input layout)
// m97 structure (unchanged this round).
// ---------------------------------------------------------------------------
template <int WRITE_BF16>
__global__ __launch_bounds__(256) void gemm_bt(
    const unsigned short* __restrict__ A, const unsigned short* __restrict__ Bt,
    void* __restrict__ Cp, int M, int N, int K, int ldc) {
  __shared__ __align__(16) unsigned short Ash[4096];  // [128][32]
  __shared__ __align__(16) unsigned short Bsh[4096];  // [128][32]

  int tiles_n = N >> 7;
  int nwg = gridDim.x;
  int wg = blockIdx.x;
  int cpx = nwg >> 3;
  wg = (wg & 7) * cpx + (wg >> 3);          // XCD-aware swizzle
  int tm = wg / tiles_n, tn = wg - tm * tiles_n;

  int tid = threadIdx.x;
  int lane = tid & 63, wave = tid >> 6;
  int wr = wave >> 1, wc = wave & 1;
  int brow = tm << 7, bcol = tn << 7;

  int fr = lane & 15, fg = lane >> 4;
  int swz = (fr >> 1) & 3;

  int srow = lane >> 2;
  int sg = (lane & 3) ^ ((srow >> 1) & 3);

  const unsigned short* aG0 = A + (size_t)(brow + wave * 32 + srow) * K + sg * 8;
  const unsigned short* aG1 = A + (size_t)(brow + wave * 32 + 16 + srow) * K + sg * 8;
  const unsigned short* bG0 = Bt + (size_t)(bcol + wave * 32 + srow) * K + sg * 8;
  const unsigned short* bG1 = Bt + (size_t)(bcol + wave * 32 + 16 + srow) * K + sg * 8;
  unsigned short* aL0 = Ash + wave * 1024;
  unsigned short* aL1 = Ash + wave * 1024 + 512;
  unsigned short* bL0 = Bsh + wave * 1024;
  unsigned short* bL1 = Bsh + wave * 1024 + 512;

  const f32x4 zero4 = {0.f, 0.f, 0.f, 0.f};
  f32x4 acc[4][4];
#pragma unroll
  for (int m = 0; m < 4; ++m)
#pragma unroll
    for (int n = 0; n < 4; ++n) acc[m][n] = zero4;

  for (int k0 = 0; k0 < K; k0 += 32) {
    GLD_LDS16(aG0 + k0, aL0);
    GLD_LDS16(aG1 + k0, aL1);
    GLD_LDS16(bG0 + k0, bL0);
    GLD_LDS16(bG1 + k0, bL1);
    __syncthreads();

    bf16x8 af[4], bfr[4];
#pragma unroll
    for (int m = 0; m < 4; ++m) {
      int r = wr * 64 + m * 16 + fr;
      af[m] = *(const bf16x8*)(Ash + r * 32 + ((fg ^ swz) * 8));
    }
#pragma unroll
    for (int n = 0; n < 4; ++n) {
      int r = wc * 64 + n * 16 + fr;
      bfr[n] = *(const bf16x8*)(Bsh + r * 32 + ((fg ^ swz) * 8));
    }
#pragma unroll
    for (int m = 0; m < 4; ++m)
#pragma unroll
      for (int n = 0; n < 4; ++n)
        acc[m][n] =
            __builtin_amdgcn_mfma_f32_16x16x32_bf16(af[m], bfr[n], acc[m][n], 0, 0, 0);
    __syncthreads();
  }

  int crow = brow + wr * 64 + fg * 4;
  int ccol = bcol + wc * 64 + fr;
#pragma unroll
  for (int m = 0; m < 4; ++m)
#pragma unroll
    for (int n = 0; n < 4; ++n)
#pragma unroll
      for (int j = 0; j < 4; ++j) {
        size_t off = (size_t)(crow + m * 16 + j) * ldc + (ccol + n * 16);
        if (WRITE_BF16)
          ((unsigned short*)Cp)[off] = f2bf(acc[m][n][j]);
        else
          ((float*)Cp)[off] = acc[m][n][j];
      }
}

// ---------------------------------------------------------------------------
// Flash attention v5: swapped QK^T + 32x32x16 MFMA, in-register softmax,
// 2-way KV-split for occupancy, conflict-free (2-way) LDS swizzles.
// Grid: 1024 blocks = (b:4, h:16, qtile:16 of 64 rows), XCD-swizzled.
// Block: 256 thr / 4 waves: wave = {qsub = w&1 (32 q-rows), kvh = w>>1
// (2048-kv half)}. Each kvh-pair stages its own K [64][64] + V^T [64][64]
// tiles (granule swizzle mask (row>>2)&7 on both: every ds_read_b128 lands
// exactly 2 lanes per bank-group = free). 32 iterations of KVBLK=64.
// Partial (m, sum, O) merged across kv-halves through reused LDS at the end.
// LDS 32 KB; __launch_bounds__(256,4) targets 4 blocks/CU = 16 waves/CU.
// ---------------------------------------------------------------------------
__global__ __launch_bounds__(256, 4) void attn_fwd(
    const unsigned short* __restrict__ qp,  // (4096, 1024), pre-scaled by SC
    const unsigned short* __restrict__ kp,  // (16384, 1024)
    const unsigned short* __restrict__ vt,  // (1024, 16384) = V^T per (b,h)
    unsigned short* __restrict__ ao) {      // (4096, 1024)
  __shared__ __align__(16) unsigned short SMEM[16384];  // 32 KB
  unsigned short* Ksh = SMEM;          // [2][64][64]
  unsigned short* Vsh = SMEM + 8192;   // [2][64][64]

  int idx = (blockIdx.x & 7) * 128 + (blockIdx.x >> 3);
  int qt = idx & 15;
  int h = (idx >> 4) & 15;
  int b = idx >> 8;
  int tid = threadIdx.x;
  int lane = tid & 63, w = tid >> 6;
  int qsub = w & 1, kvh = w >> 1;
  int q5 = lane & 31, hi = lane >> 5;

  // ---- Q fragments (B-operand, 32x32x16): lane q5, k = s*16 + hi*8 + e ----
  const unsigned short* qptr =
      qp + (size_t)(b * 1024 + qt * 64 + qsub * 32 + q5) * 1024 + h * 64 + hi * 8;
  bf16x8 qf[4];
#pragma unroll
  for (int s = 0; s < 4; ++s) qf[s] = *(const bf16x8*)(qptr + s * 16);

  bf16x8 ones;
#pragma unroll
  for (int e = 0; e < 8; ++e) ones[e] = (short)0x3F80;  // 1.0 bf16

  f32x16 O0, O1, rsum;
#pragma unroll
  for (int r = 0; r < 16; ++r) { O0[r] = 0.f; O1[r] = 0.f; rsum[r] = 0.f; }
  float mrun = -1e30f;

  // ---- staging bases: issue i covers rows qsub*32+i*8 .. +7, granule
  // g_dst = lane&7, source granule = g_dst ^ ((row>>2)&7) = lx ^ ((2i)&7) ----
  int lx = (lane & 7) ^ hi;
  int srow = lane >> 3;  // 0..7
  const unsigned short* kbase =
      kp + (size_t)(b * 4096 + kvh * 2048 + qsub * 32 + srow) * 1024 + h * 64;
  const unsigned short* vbase =
      vt + (size_t)(h * 64 + qsub * 32 + srow) * 16384 + b * 4096 + kvh * 2048;
  unsigned short* kdst = Ksh + kvh * 4096 + qsub * 2048;
  unsigned short* vdst = Vsh + kvh * 4096 + qsub * 2048;

  // ---- read-side slot offsets: slot = (2*c2) ^ hi ^ ((q5>>2)&7) ----
  int hm = hi ^ ((q5 >> 2) & 7);
  int soff[4];
#pragma unroll
  for (int c2 = 0; c2 < 4; ++c2) soff[c2] = ((2 * c2) ^ hm) * 8;
  const unsigned short* kr = Ksh + kvh * 4096 + q5 * 64;
  const unsigned short* vr = Vsh + kvh * 4096 + q5 * 64;

  for (int it = 0; it < 32; ++it) {
    size_t kadv = (size_t)it * 65536;
    int vadv = it * 64;
#pragma unroll
    for (int i = 0; i < 4; ++i) {
      int gs = (lx ^ ((2 * i) & 7)) * 8;
      GLD_LDS16(kbase + kadv + i * 8192 + gs, kdst + i * 512);
      GLD_LDS16(vbase + vadv + (size_t)i * 131072 + gs, vdst + i * 512);
    }
    __syncthreads();  // drains vmcnt; tiles ready

    // ---- S^T = K Q^T : 2 kv-subtiles x 4 d-slices ----
    f32x16 S0, S1;
#pragma unroll
    for (int r = 0; r < 16; ++r) { S0[r] = 0.f; S1[r] = 0.f; }
    __builtin_amdgcn_s_setprio(1);
#pragma unroll
    for (int s = 0; s < 4; ++s) {
      bf16x8 kf0 = *(const bf16x8*)(kr + soff[s]);
      bf16x8 kf1 = *(const bf16x8*)(kr + 2048 + soff[s]);
      S0 = __builtin_amdgcn_mfma_f32_32x32x16_bf16(kf0, qf[s], S0, 0, 0, 0);
      S1 = __builtin_amdgcn_mfma_f32_32x32x16_bf16(kf1, qf[s], S1, 0, 0, 0);
    }
    __builtin_amdgcn_s_setprio(0);

    // ---- row max: pair tree over 32 values + one cross-half shuffle ----
    float ta[8];
#pragma unroll
    for (int j = 0; j < 8; ++j)
      ta[j] = fmaxf(fmaxf(S0[j], S0[j + 8]), fmaxf(S1[j], S1[j + 8]));
    float c0 = fmaxf(fmaxf(ta[0], ta[4]), fmaxf(ta[1], ta[5]));
    float c1 = fmaxf(fmaxf(ta[2], ta[6]), fmaxf(ta[3], ta[7]));
    float cmax = fmaxf(c0, c1);
    cmax = fmaxf(cmax, __shfl_xor(cmax, 32));

    // ---- rescale only when running max grows (skip is exact) ----
    if (__any(cmax > mrun)) {
      float mn = fmaxf(mrun, cmax);
      float fsc = exp2f(mrun - mn);
      mrun = mn;
      rsum[0] *= fsc;  // only [0] is ever read
#pragma unroll
      for (int r = 0; r < 16; ++r) { O0[r] *= fsc; O1[r] *= fsc; }
    }

    // ---- per kv-subtile: exp2 in place, pack to B-frags, rsum + PV ----
#define PACK_PV(SK, KT)                                                       \
    {                                                                         \
      _Pragma("unroll")                                                       \
      for (int r = 0; r < 16; ++r) SK[r] = exp2f(SK[r] - mrun);               \
      unsigned u[8];                                                          \
      _Pragma("unroll")                                                       \
      for (int i2 = 0; i2 < 8; ++i2) {                                        \
        __hip_bfloat162 pk =                                                  \
            __float22bfloat162_rn(float2{SK[2 * i2], SK[2 * i2 + 1]});        \
        u[i2] = *reinterpret_cast<unsigned*>(&pk);                            \
      }                                                                       \
      pl32swap(u[0], u[2]); pl32swap(u[1], u[3]);                             \
      pl32swap(u[4], u[6]); pl32swap(u[5], u[7]);                             \
      union PU { unsigned uu[4]; bf16x8 v; };                                 \
      PU a0; a0.uu[0] = u[0]; a0.uu[1] = u[1]; a0.uu[2] = u[2]; a0.uu[3] = u[3]; \
      PU a1; a1.uu[0] = u[4]; a1.uu[1] = u[5]; a1.uu[2] = u[6]; a1.uu[3] = u[7]; \
      bf16x8 pf0 = a0.v, pf1 = a1.v;                                          \
      __builtin_amdgcn_s_setprio(1);                                          \
      rsum = __builtin_amdgcn_mfma_f32_32x32x16_bf16(ones, pf0, rsum, 0, 0, 0); \
      rsum = __builtin_amdgcn_mfma_f32_32x32x16_bf16(ones, pf1, rsum, 0, 0, 0); \
      bf16x8 vf;                                                              \
      vf = *(const bf16x8*)(vr + soff[2 * KT + 0]);                           \
      O0 = __builtin_amdgcn_mfma_f32_32x32x16_bf16(vf, pf0, O0, 0, 0, 0);     \
      vf = *(const bf16x8*)(vr + soff[2 * KT + 1]);                           \
      O0 = __builtin_amdgcn_mfma_f32_32x32x16_bf16(vf, pf1, O0, 0, 0, 0);     \
      vf = *(const bf16x8*)(vr + 2048 + soff[2 * KT + 0]);                    \
      O1 = __builtin_amdgcn_mfma_f32_32x32x16_bf16(vf, pf0, O1, 0, 0, 0);     \
      vf = *(const bf16x8*)(vr + 2048 + soff[2 * KT + 1]);                    \
      O1 = __builtin_amdgcn_mfma_f32_32x32x16_bf16(vf, pf1, O1, 0, 0, 0);     \
      __builtin_amdgcn_s_setprio(0);                                          \
    }

    PACK_PV(S0, 0)
    PACK_PV(S1, 1)
#undef PACK_PV

    __syncthreads();  // all LDS reads done before next stage overwrites
  }

  // ---- merge kv-halves through reused LDS ----
  float* fb = (float*)SMEM;           // [64 q][68 d] floats
  float* bm = fb + 4352;              // [64]
  float* bs = fb + 4416;              // [64]
  int qrow_l = qsub * 32 + q5;
  if (kvh == 1) {
    float* rowp = fb + qrow_l * 68;
#pragma unroll
    for (int r = 0; r < 16; ++r) {
      int d = (r & 3) + 8 * (r >> 2) + 4 * hi;
      rowp[d] = O0[r];
      rowp[32 + d] = O1[r];
    }
    bm[qrow_l] = mrun;
    bs[qrow_l] = rsum[0];
  }
  __syncthreads();
  if (kvh == 0) {
    float m2 = bm[qrow_l], s2 = bs[qrow_l];
    float ms = fmaxf(mrun, m2);
    float f1 = exp2f(mrun - ms), f2 = exp2f(m2 - ms);
    float inv = 1.0f / (rsum[0] * f1 + s2 * f2);
    f1 *= inv; f2 *= inv;
    float* rowp = fb + qrow_l * 68;
    size_t obase = (size_t)(b * 1024 + qt * 64 + qrow_l) * 1024 + h * 64;
#pragma unroll
    for (int c = 0; c < 4; ++c) {
      f32x4 o2 = *(const f32x4*)(rowp + 8 * c + 4 * hi);
      ushort4 pk;
      pk.x = f2bf(O0[4 * c + 0] * f1 + o2[0] * f2);
      pk.y = f2bf(O0[4 * c + 1] * f1 + o2[1] * f2);
      pk.z = f2bf(O0[4 * c + 2] * f1 + o2[2] * f2);
      pk.w = f2bf(O0[4 * c + 3] * f1 + o2[3] * f2);
      *(ushort4*)(ao + obase + c * 8 + hi * 4) = pk;
    }
#pragma unroll
    for (int c = 0; c < 4; ++c) {
      f32x4 o2 = *(const f32x4*)(rowp + 32 + 8 * c + 4 * hi);
      ushort4 pk;
      pk.x = f2bf(O1[4 * c + 0] * f1 + o2[0] * f2);
      pk.y = f2bf(O1[4 * c + 1] * f1 + o2[1] * f2);
      pk.z = f2bf(O1[4 * c + 2] * f1 + o2[2] * f2);
      pk.w = f2bf(O1[4 * c + 3] * f1 + o2[3] * f2);
      *(ushort4*)(ao + obase + 32 + c * 8 + hi * 4) = pk;
    }
  }
}

// ---------------------------------------------------------------------------
// Launcher. Workspace layout (128 MiB):
//   [0,8)    q_bf     [8,40)  kv_bf    [40,48) weights bf16 x4
//   [48,56)  qproj    [56,88) kproj    [88,120) v^T proj   [120,128) attn out
// ---------------------------------------------------------------------------
extern "C" void kernel_launch(void* const* d_in, const int* in_sizes, int n_in,
                              void* d_out, int out_size, void* d_ws, size_t ws_size,
                              hipStream_t stream) {
  const float* query = (const float*)d_in[0];
  const float* kvs = (const float*)d_in[1];
  const float* wq = (const float*)d_in[2];
  const float* wk = (const float*)d_in[3];
  const float* wv = (const float*)d_in[4];
  const float* wo = (const float*)d_in[5];
  float* out = (float*)d_out;
  char* ws = (char*)d_ws;
  const size_t MB = 1ull << 20;

  unsigned short* q_bf = (unsigned short*)(ws + 0 * MB);
  unsigned short* kv_bf = (unsigned short*)(ws + 8 * MB);
  unsigned short* wq_bf = (unsigned short*)(ws + 40 * MB);
  unsigned short* wk_bf = (unsigned short*)(ws + 42 * MB);
  unsigned short* wv_bf = (unsigned short*)(ws + 44 * MB);
  unsigned short* wo_bf = (unsigned short*)(ws + 46 * MB);
  unsigned short* qp = (unsigned short*)(ws + 48 * MB);
  unsigned short* kp = (unsigned short*)(ws + 56 * MB);
  unsigned short* vt = (unsigned short*)(ws + 88 * MB);
  unsigned short* ao = (unsigned short*)(ws + 120 * MB);

  cvt_all<<<2048, 256, 0, stream>>>(query, kvs, wq, wk, wv, wo, q_bf, kv_bf,
                                    wq_bf, wk_bf, wv_bf, wo_bf);

  // q = query @ (Wq*SC)^T       (4096 x 1024)
  gemm_bt<1><<<256, 256, 0, stream>>>(q_bf, wq_bf, qp, 4096, 1024, 1024, 1024);
  // k = kv @ Wk^T               (16384 x 1024)
  gemm_bt<1><<<1024, 256, 0, stream>>>(kv_bf, wk_bf, kp, 16384, 1024, 1024, 1024);
  // v^T = Wv @ kv^T             (1024 x 16384)
  gemm_bt<1><<<1024, 256, 0, stream>>>(wv_bf, kv_bf, vt, 1024, 16384, 1024, 16384);

  attn_fwd<<<1024, 256, 0, stream>>>(qp, kp, vt, ao);

  // out = attn_out @ Wo^T       (4096 x 1024) f32
  gemm_bt<0><<<256, 256, 0, stream>>>(ao, wo_bf, out, 4096, 1024, 1024, 1024);
}